// Round 4
// baseline (268.313 us; speedup 1.0000x reference)
//
#include <hip/hip_runtime.h>
#include <hip/hip_bf16.h>

typedef unsigned short u16;
typedef unsigned int u32;
typedef __attribute__((ext_vector_type(8))) short short8;
typedef __attribute__((ext_vector_type(4))) float f32x4;

// cheap RNE f32->bf16 (finite values only)
__device__ __forceinline__ u16 f2b(float f) {
  u32 u = __builtin_bit_cast(u32, f);
  u += 0x7fffu + ((u >> 16) & 1u);
  return (u16)(u >> 16);
}
__device__ __forceinline__ u32 pkb(float a, float b) {
  u32 ua = __builtin_bit_cast(u32, a);
  u32 ub = __builtin_bit_cast(u32, b);
  ua += 0x7fffu + ((ua >> 16) & 1u);
  ub += 0x7fffu + ((ub >> 16) & 1u);
  return (ua >> 16) | (ub & 0xffff0000u);
}
__device__ __forceinline__ float b2f(u16 u) {
  u32 x = ((u32)u) << 16;
  return __builtin_bit_cast(float, x);
}
__device__ __forceinline__ void load_lds16(const u16* g, u16* l) {
  __builtin_amdgcn_global_load_lds(
      (const __attribute__((address_space(1))) void*)(uintptr_t)g,
      (__attribute__((address_space(3))) void*)(u32)(uintptr_t)l, 16, 0, 0);
}

// k-slot permutation (64-granular): slot(k) = (k>>6)*64 + (k&15)*4 + ((k>>4)&3)

// ---- K_prep: fused ln_msa (blocks 0..8191) + ln_pair (8192..9215) +
//      weight conversion (9216..10495) ----
__global__ __launch_bounds__(256) void k_prep(
    const float* __restrict__ msa, const float* __restrict__ qns,
    const float* __restrict__ qnb, const float* __restrict__ pair,
    const float* __restrict__ pns, const float* __restrict__ pnb,
    const float* __restrict__ fw, const float* __restrict__ qw,
    const float* __restrict__ kw, const float* __restrict__ vw,
    const float* __restrict__ gw, const float* __restrict__ ow,
    u16* __restrict__ xb, float* __restrict__ biasB,
    u16* __restrict__ Wt, u16* __restrict__ OWt) {
  __shared__ float plds[512];
  const int tid = threadIdx.x, blk = blockIdx.x;
  if (blk < 8192) {
    // ---- LayerNorm(msa_act) -> xb bf16 [32768][256] ----
    const int wid = tid >> 6, lane = tid & 63;
    const int row = blk * 4 + wid;
    const float4 v = ((const float4*)(msa + (size_t)row * 256))[lane];
    float s = v.x + v.y + v.z + v.w;
    float s2 = v.x * v.x + v.y * v.y + v.z * v.z + v.w * v.w;
#pragma unroll
    for (int m = 1; m < 64; m <<= 1) { s += __shfl_xor(s, m); s2 += __shfl_xor(s2, m); }
    const float mu = s * (1.f / 256.f);
    const float r = rsqrtf(s2 * (1.f / 256.f) - mu * mu + 1e-5f);
    const int c0 = lane * 4;
    const float4 scv = ((const float4*)qns)[lane];
    const float4 biv = ((const float4*)qnb)[lane];
    uint2 o;
    o.x = pkb((v.x - mu) * r * scv.x + biv.x, (v.y - mu) * r * scv.y + biv.y);
    o.y = pkb((v.z - mu) * r * scv.z + biv.z, (v.w - mu) * r * scv.w + biv.w);
    *(uint2*)(xb + (size_t)row * 256 + c0) = o;
  } else if (blk < 9216) {
    // ---- LayerNorm(pair_act) + feat2d -> biasB[h][q][slot], coalesced ----
    const int pb = blk - 8192;          // 64 rows per block
    const int ra = tid >> 3, hh = tid & 7;
    const int c0 = hh * 16;
#pragma unroll
    for (int rr = 0; rr < 2; rr++) {
      const int R = pb * 64 + ra + rr * 32;   // R = q*256 + k
      const float4* src = (const float4*)(pair + (size_t)R * 128 + c0);
      const float4 a0 = src[0], a1 = src[1], a2 = src[2], a3 = src[3];
      float xs[16] = {a0.x, a0.y, a0.z, a0.w, a1.x, a1.y, a1.z, a1.w,
                      a2.x, a2.y, a2.z, a2.w, a3.x, a3.y, a3.z, a3.w};
      float s = 0.f, s2 = 0.f;
#pragma unroll
      for (int c = 0; c < 16; c++) { s += xs[c]; s2 += xs[c] * xs[c]; }
#pragma unroll
      for (int m = 1; m < 8; m <<= 1) { s += __shfl_xor(s, m); s2 += __shfl_xor(s2, m); }
      const float mu = s * (1.f / 128.f);
      const float r = rsqrtf(s2 * (1.f / 128.f) - mu * mu + 1e-5f);
      float ph[8] = {0.f, 0.f, 0.f, 0.f, 0.f, 0.f, 0.f, 0.f};
#pragma unroll
      for (int c = 0; c < 16; c++) {
        const float xn = (xs[c] - mu) * r * pns[c0 + c] + pnb[c0 + c];
        const float4 w0 = *(const float4*)(fw + (c0 + c) * 8);
        const float4 w1 = *(const float4*)(fw + (c0 + c) * 8 + 4);
        ph[0] += xn * w0.x; ph[1] += xn * w0.y; ph[2] += xn * w0.z; ph[3] += xn * w0.w;
        ph[4] += xn * w1.x; ph[5] += xn * w1.y; ph[6] += xn * w1.z; ph[7] += xn * w1.w;
      }
#pragma unroll
      for (int m = 1; m < 8; m <<= 1) {
#pragma unroll
        for (int h = 0; h < 8; h++) ph[h] += __shfl_xor(ph[h], m);
      }
      const int kl = R & 63;
      const int sl = ((kl & 15) << 2) | ((kl >> 4) & 3);
      plds[hh * 64 + sl] = ph[hh];
    }
    __syncthreads();
    const int q = (pb * 64) >> 8, g = pb & 3;
    const int j = tid * 2;
    *(float2*)(biasB + (j >> 6) * 65536 + q * 256 + g * 64 + (j & 63)) =
        *(const float2*)(plds + j);
  } else {
    // ---- weights -> bf16 transposed [N][K] ----
    const int idx = (blk - 9216) * 256 + tid;
    if (idx < 262144) {
      const int a = idx & 255, nl = (idx >> 8) & 255, proj = idx >> 16;
      const float* w = proj == 0 ? qw : proj == 1 ? kw : proj == 2 ? vw : gw;
      float val = w[a * 256 + nl];
      if (proj == 0) val *= 0.17677669529663687f;  // 1/sqrt(32) folded into q_w
      Wt[idx] = f2b(val);
    } else {
      const int i2 = idx - 262144;
      const int o = i2 >> 8, j = i2 & 255;
      OWt[i2] = f2b(ow[j * 256 + o]);  // o_w[h][c][o] -> OWt[o][h*32+c]
    }
  }
}

// ------ K4/K6: bf16 MFMA GEMM, A[M][256] @ Bt[N][256]^T, 128x128 tile,
//        global_load_lds(16B) staging, two 32-k panels per barrier round ------
template <bool OUT_BF16>
__global__ __launch_bounds__(256) void k_gemm(
    const u16* __restrict__ A, const u16* __restrict__ Bt,
    void* __restrict__ out, const float* __restrict__ obias, const int N) {
  __shared__ u16 As[2][128 * 32];
  __shared__ u16 Bs[2][128 * 32];
  const int tid = threadIdx.x, wid = tid >> 6, lane = tid & 63;
  const int quad = lane >> 4, l16 = lane & 15;
  const int wm = (wid >> 1) * 64, wn = (wid & 1) * 64;
  const int bm = blockIdx.x, bn = blockIdx.y;
  const int r0 = wid * 16 + (lane >> 2);
  const int kc = (lane & 3) * 8;
  const u16* gA0 = A + (size_t)(bm * 128 + r0) * 256 + kc;
  const u16* gA1 = A + (size_t)(bm * 128 + 64 + r0) * 256 + kc;
  const u16* gB0 = Bt + (size_t)(bn * 128 + r0) * 256 + kc;
  const u16* gB1 = Bt + (size_t)(bn * 128 + 64 + r0) * 256 + kc;
  u16* lA0 = As[0] + wid * 512;
  u16* lA1 = As[0] + 2048 + wid * 512;
  u16* lB0 = Bs[0] + wid * 512;
  u16* lB1 = Bs[0] + 2048 + wid * 512;
  f32x4 acc[4][4];
#pragma unroll
  for (int i = 0; i < 4; i++)
#pragma unroll
    for (int j = 0; j < 4; j++) acc[i][j] = f32x4{0.f, 0.f, 0.f, 0.f};
  for (int k0 = 0; k0 < 256; k0 += 64) {
    __syncthreads();
    load_lds16(gA0 + k0, lA0);
    load_lds16(gA1 + k0, lA1);
    load_lds16(gB0 + k0, lB0);
    load_lds16(gB1 + k0, lB1);
    load_lds16(gA0 + k0 + 32, lA0 + 4096);
    load_lds16(gA1 + k0 + 32, lA1 + 4096);
    load_lds16(gB0 + k0 + 32, lB0 + 4096);
    load_lds16(gB1 + k0 + 32, lB1 + 4096);
    __syncthreads();
#pragma unroll
    for (int ks = 0; ks < 2; ks++) {
      short8 af[4], bf[4];
#pragma unroll
      for (int i = 0; i < 4; i++)
        af[i] = *(const short8*)(As[ks] + (wm + i * 16 + l16) * 32 + quad * 8);
#pragma unroll
      for (int j = 0; j < 4; j++)
        bf[j] = *(const short8*)(Bs[ks] + (wn + j * 16 + l16) * 32 + quad * 8);
#pragma unroll
      for (int i = 0; i < 4; i++)
#pragma unroll
        for (int j = 0; j < 4; j++)
          acc[i][j] = __builtin_amdgcn_mfma_f32_16x16x32_bf16(af[i], bf[j], acc[i][j], 0, 0, 0);
    }
  }
#pragma unroll
  for (int i = 0; i < 4; i++)
#pragma unroll
    for (int j = 0; j < 4; j++)
#pragma unroll
      for (int r = 0; r < 4; r++) {
        const int gm = bm * 128 + wm + i * 16 + quad * 4 + r;
        const int gn = bn * 128 + wn + j * 16 + l16;
        const float v = acc[i][j][r];
        if (OUT_BF16) ((u16*)out)[(size_t)gm * N + gn] = f2b(v);
        else ((float*)out)[(size_t)gm * N + gn] = v + obias[gn];
      }
}

// ---- K5: attention, block = (b, h, q-half): 512 thr = 8 waves x 16 q.
//      K in LDS (union-reused as P after softmax barrier); V^T permuted;
//      no max-subtraction (logits bounded; masked terms underflow to 0) ----
__global__ __launch_bounds__(512, 4) void k_attn(
    const u16* __restrict__ Y, const float* __restrict__ biasB,
    const float* __restrict__ mask, const float* __restrict__ gb,
    u16* __restrict__ Z) {
  __shared__ u16 KsPs[9216];   // Ks [256][32] (8192 u16), later per-wave Ps (8x1152)
  __shared__ u16 Vt[32 * 264]; // [c][slot], stride 264 = 8*33 (2-way-only aliasing)
  const int b = blockIdx.x, h = blockIdx.y, qh = blockIdx.z;
  const int tid = threadIdx.x, w = tid >> 6, lane = tid & 63;
  const int quad = lane >> 4, l16 = lane & 15;
  const int q0 = qh * 128 + w * 16;
  const u16* Yb = Y + (size_t)b * 256 * 1024;
  // ---- stage K [k][32c of head h] via async 16B loads (2 per wave) ----
  {
    const int kr = w * 32 + (lane >> 2), kc = (lane & 3) * 8;
    load_lds16(Yb + (size_t)kr * 1024 + 256 + h * 32 + kc, KsPs + (w * 32) * 32);
    load_lds16(Yb + (size_t)(kr + 16) * 1024 + 256 + h * 32 + kc, KsPs + (w * 32 + 16) * 32);
  }
  // ---- stage V^T permuted: thread t -> slot t&255, c-chunk (t>>8)*16 ----
  {
    const int slot = tid & 255, c0 = (tid >> 8) * 16;
    const int kv = ((slot >> 6) << 6) + ((slot & 3) << 4) + ((slot >> 2) & 15);
    const u16* src = Yb + (size_t)kv * 1024 + 512 + h * 32 + c0;
    union { uint4 q[2]; u16 u[16]; } uu;
    uu.q[0] = *(const uint4*)(src);
    uu.q[1] = *(const uint4*)(src + 8);
#pragma unroll
    for (int j = 0; j < 16; j++) Vt[(c0 + j) * 264 + slot] = uu.u[j];
  }
  // ---- Q frag + mask (global, before barrier) ----
  const short8 aq = *(const short8*)(Yb + (size_t)(q0 + l16) * 1024 + h * 32 + quad * 8);
  float maskv[16];
#pragma unroll
  for (int ni = 0; ni < 16; ni++)
    maskv[ni] = 1e9f * (mask[b * 256 + ni * 16 + l16] - 1.f);
  __syncthreads();  // K + V staging complete
  // ---- S = Q K^T : 16 MFMAs per wave ----
  f32x4 S[16];
#pragma unroll
  for (int ni = 0; ni < 16; ni++) S[ni] = f32x4{0.f, 0.f, 0.f, 0.f};
#pragma unroll
  for (int ni = 0; ni < 16; ni++) {
    const short8 bk = *(const short8*)(KsPs + (ni * 16 + l16) * 32 + quad * 8);
    S[ni] = __builtin_amdgcn_mfma_f32_16x16x32_bf16(aq, bk, S[ni], 0, 0, 0);
  }
  // ---- + permuted pair bias + mask; softmax over k WITHOUT max-sub ----
  float li[4];
#pragma unroll
  for (int r = 0; r < 4; r++) {
    const int qg = q0 + quad * 4 + r;
    const float* bb = biasB + (h << 16) + (qg << 8) + l16 * 4;
    const float4 b0 = *(const float4*)(bb);
    const float4 b1 = *(const float4*)(bb + 64);
    const float4 b2 = *(const float4*)(bb + 128);
    const float4 b3 = *(const float4*)(bb + 192);
    const float bv[16] = {b0.x, b0.y, b0.z, b0.w, b1.x, b1.y, b1.z, b1.w,
                          b2.x, b2.y, b2.z, b2.w, b3.x, b3.y, b3.z, b3.w};
    float l = 0.f;
#pragma unroll
    for (int ni = 0; ni < 16; ni++) {
      const float p = __expf(S[ni][r] + bv[ni] + maskv[ni]);
      S[ni][r] = p;
      l += p;
    }
#pragma unroll
    for (int d = 1; d < 16; d <<= 1) l += __shfl_xor(l, d);
    li[r] = __builtin_amdgcn_rcpf(l);
  }
  __syncthreads();  // all K-reads done; Ks region becomes per-wave Ps
  // ---- P @ V in 4 k-quarters through per-wave LDS (wave-in-order DS) ----
  f32x4 O[2];
  O[0] = f32x4{0.f, 0.f, 0.f, 0.f};
  O[1] = f32x4{0.f, 0.f, 0.f, 0.f};
  u16* Pw = KsPs + w * 1152;  // [16 q][72]
#pragma unroll
  for (int Q = 0; Q < 4; Q++) {
#pragma unroll
    for (int r = 0; r < 4; r++) {
      uint2 wv;  // slots l16*4..+3 of row quad*4+r
      wv.x = pkb(S[Q * 4 + 0][r], S[Q * 4 + 1][r]);
      wv.y = pkb(S[Q * 4 + 2][r], S[Q * 4 + 3][r]);
      *(uint2*)(Pw + (quad * 4 + r) * 72 + l16 * 4) = wv;
    }
#pragma unroll
    for (int ks = 0; ks < 2; ks++) {
      const short8 ap = *(const short8*)(Pw + l16 * 72 + ks * 32 + quad * 8);
#pragma unroll
      for (int nj = 0; nj < 2; nj++) {
        const short8 bv = *(const short8*)(Vt + (nj * 16 + l16) * 264 + Q * 64 + ks * 32 + quad * 8);
        O[nj] = __builtin_amdgcn_mfma_f32_16x16x32_bf16(ap, bv, O[nj], 0, 0, 0);
      }
    }
  }
  // ---- epilogue: 1/l, gate sigmoid, stage in Pw, coalesced 16B stores ----
  const float* gbh = gb + h * 32;
#pragma unroll
  for (int nj = 0; nj < 2; nj++)
#pragma unroll
    for (int r = 0; r < 4; r++) {
      const int qg = q0 + quad * 4 + r;
      const int c = nj * 16 + l16;
      const float wa = O[nj][r] * li[r];
      const float gv = b2f(Yb[(size_t)qg * 1024 + 768 + h * 32 + c]) + gbh[c];
      const float gate = __builtin_amdgcn_rcpf(1.f + __expf(-gv));
      Pw[(quad * 4 + r) * 40 + c] = f2b(wa * gate);
    }
  {
    const int qr = lane >> 2, cc = (lane & 3) * 8;
    const uint4 zv = *(const uint4*)(Pw + qr * 40 + cc);
    *(uint4*)(Z + ((size_t)(b * 256 + q0 + qr)) * 256 + h * 32 + cc) = zv;
  }
}

extern "C" void kernel_launch(void* const* d_in, const int* in_sizes, int n_in,
                              void* d_out, int out_size, void* d_ws, size_t ws_size,
                              hipStream_t stream) {
  const float* msa  = (const float*)d_in[0];
  const float* mask = (const float*)d_in[1];
  const float* pair = (const float*)d_in[2];
  const float* qns  = (const float*)d_in[3];
  const float* qnb  = (const float*)d_in[4];
  const float* pns  = (const float*)d_in[5];
  const float* pnb  = (const float*)d_in[6];
  const float* f2w  = (const float*)d_in[7];
  const float* qw   = (const float*)d_in[8];
  const float* kw   = (const float*)d_in[9];
  const float* vw   = (const float*)d_in[10];
  const float* gw   = (const float*)d_in[11];
  const float* gbp  = (const float*)d_in[12];
  const float* ow   = (const float*)d_in[13];
  const float* ob   = (const float*)d_in[14];
  float* out = (float*)d_out;
  char* ws = (char*)d_ws;
  u16*   xb    = (u16*)(ws);                  // 16777216 B
  u16*   Wt    = (u16*)(ws + 16777216);       //   524288 B
  u16*   OWt   = (u16*)(ws + 17301504);       //   131072 B
  float* biasB = (float*)(ws + 17432576);     //  2097152 B
  u16*   Y     = (u16*)(ws + 19529728);       // 67108864 B
  u16*   Z     = (u16*)(ws + 86638592);       // 16777216 B

  k_prep<<<10496, 256, 0, stream>>>(msa, qns, qnb, pair, pns, pnb, f2w,
                                    qw, kw, vw, gw, ow, xb, biasB, Wt, OWt);
  k_gemm<true><<<dim3(256, 8), 256, 0, stream>>>(xb, Wt, (void*)Y, nullptr, 1024);
  k_attn<<<dim3(128, 8, 2), 512, 0, stream>>>(Y, biasB, mask, gbp, Z);
  k_gemm<false><<<dim3(256, 2), 256, 0, stream>>>(Z, OWt, (void*)out, ob, 256);
}

// Round 5
// 243.356 us; speedup vs baseline: 1.1026x; 1.1026x over previous
//
#include <hip/hip_runtime.h>
#include <hip/hip_bf16.h>

typedef unsigned short u16;
typedef unsigned int u32;
typedef __attribute__((ext_vector_type(8))) short short8;
typedef __attribute__((ext_vector_type(4))) float f32x4;

// cheap RNE f32->bf16 (finite values only)
__device__ __forceinline__ u16 f2b(float f) {
  u32 u = __builtin_bit_cast(u32, f);
  u += 0x7fffu + ((u >> 16) & 1u);
  return (u16)(u >> 16);
}
__device__ __forceinline__ u32 pkb(float a, float b) {
  u32 ua = __builtin_bit_cast(u32, a);
  u32 ub = __builtin_bit_cast(u32, b);
  ua += 0x7fffu + ((ua >> 16) & 1u);
  ub += 0x7fffu + ((ub >> 16) & 1u);
  return (ua >> 16) | (ub & 0xffff0000u);
}
__device__ __forceinline__ float b2f(u16 u) {
  u32 x = ((u32)u) << 16;
  return __builtin_bit_cast(float, x);
}
__device__ __forceinline__ void load_lds16(const u16* g, u16* l) {
  __builtin_amdgcn_global_load_lds(
      (const __attribute__((address_space(1))) void*)(uintptr_t)g,
      (__attribute__((address_space(3))) void*)(u32)(uintptr_t)l, 16, 0, 0);
}

// k-slot permutation (64-granular): slot(k) = (k>>6)*64 + (k&15)*4 + ((k>>4)&3)

// ---- K_prep: blocks 0..2047 ln_msa (16 rows/block, MLP=4) |
//      2048..3071 ln_pair | 3072..3151 weight transpose via LDS ----
__global__ __launch_bounds__(256) void k_prep(
    const float* __restrict__ msa, const float* __restrict__ qns,
    const float* __restrict__ qnb, const float* __restrict__ pair,
    const float* __restrict__ pns, const float* __restrict__ pnb,
    const float* __restrict__ fw, const float* __restrict__ qw,
    const float* __restrict__ kw, const float* __restrict__ vw,
    const float* __restrict__ gw, const float* __restrict__ ow,
    u16* __restrict__ xb, float* __restrict__ biasB,
    u16* __restrict__ Wt, u16* __restrict__ OWt) {
  __shared__ float plds[512];
  __shared__ u16 tlds[64 * 66];
  const int tid = threadIdx.x, blk = blockIdx.x;
  if (blk < 2048) {
    // ---- LayerNorm(msa_act): 4 waves x 4 rows; lane = r*16 + c ----
    const int wid = tid >> 6, lane = tid & 63;
    const int r = lane >> 4, c = lane & 15;
    const int row = blk * 16 + wid * 4 + r;
    const float* src = msa + (size_t)row * 256;
    float4 v[4];
#pragma unroll
    for (int it = 0; it < 4; it++)
      v[it] = *(const float4*)(src + it * 64 + c * 4);  // 4 independent loads
    float s = 0.f, s2 = 0.f;
#pragma unroll
    for (int it = 0; it < 4; it++) {
      s += v[it].x + v[it].y + v[it].z + v[it].w;
      s2 += v[it].x * v[it].x + v[it].y * v[it].y + v[it].z * v[it].z + v[it].w * v[it].w;
    }
#pragma unroll
    for (int m = 1; m < 16; m <<= 1) { s += __shfl_xor(s, m); s2 += __shfl_xor(s2, m); }
    const float mu = s * (1.f / 256.f);
    const float rs = rsqrtf(s2 * (1.f / 256.f) - mu * mu + 1e-5f);
    u16* dst = xb + (size_t)row * 256;
#pragma unroll
    for (int it = 0; it < 4; it++) {
      const int c0 = it * 64 + c * 4;
      const float4 scv = *(const float4*)(qns + c0);
      const float4 biv = *(const float4*)(qnb + c0);
      uint2 o;
      o.x = pkb((v[it].x - mu) * rs * scv.x + biv.x, (v[it].y - mu) * rs * scv.y + biv.y);
      o.y = pkb((v[it].z - mu) * rs * scv.z + biv.z, (v[it].w - mu) * rs * scv.w + biv.w);
      *(uint2*)(dst + c0) = o;
    }
  } else if (blk < 3072) {
    // ---- LayerNorm(pair_act) + feat2d -> biasB[h][q][slot], coalesced ----
    const int pb = blk - 2048;          // 64 rows per block
    const int ra = tid >> 3, hh = tid & 7;
    const int c0 = hh * 16;
#pragma unroll
    for (int rr = 0; rr < 2; rr++) {
      const int R = pb * 64 + ra + rr * 32;   // R = q*256 + k
      const float4* src = (const float4*)(pair + (size_t)R * 128 + c0);
      const float4 a0 = src[0], a1 = src[1], a2 = src[2], a3 = src[3];
      float xs[16] = {a0.x, a0.y, a0.z, a0.w, a1.x, a1.y, a1.z, a1.w,
                      a2.x, a2.y, a2.z, a2.w, a3.x, a3.y, a3.z, a3.w};
      float s = 0.f, s2 = 0.f;
#pragma unroll
      for (int c = 0; c < 16; c++) { s += xs[c]; s2 += xs[c] * xs[c]; }
#pragma unroll
      for (int m = 1; m < 8; m <<= 1) { s += __shfl_xor(s, m); s2 += __shfl_xor(s2, m); }
      const float mu = s * (1.f / 128.f);
      const float r = rsqrtf(s2 * (1.f / 128.f) - mu * mu + 1e-5f);
      float ph[8] = {0.f, 0.f, 0.f, 0.f, 0.f, 0.f, 0.f, 0.f};
#pragma unroll
      for (int c = 0; c < 16; c++) {
        const float xn = (xs[c] - mu) * r * pns[c0 + c] + pnb[c0 + c];
        const float4 w0 = *(const float4*)(fw + (c0 + c) * 8);
        const float4 w1 = *(const float4*)(fw + (c0 + c) * 8 + 4);
        ph[0] += xn * w0.x; ph[1] += xn * w0.y; ph[2] += xn * w0.z; ph[3] += xn * w0.w;
        ph[4] += xn * w1.x; ph[5] += xn * w1.y; ph[6] += xn * w1.z; ph[7] += xn * w1.w;
      }
#pragma unroll
      for (int m = 1; m < 8; m <<= 1) {
#pragma unroll
        for (int h = 0; h < 8; h++) ph[h] += __shfl_xor(ph[h], m);
      }
      const int kl = R & 63;
      const int sl = ((kl & 15) << 2) | ((kl >> 4) & 3);
      plds[hh * 64 + sl] = ph[hh];
    }
    __syncthreads();
    const int q = (pb * 64) >> 8, g = pb & 3;
    const int j = tid * 2;
    *(float2*)(biasB + (j >> 6) * 65536 + q * 256 + g * 64 + (j & 63)) =
        *(const float2*)(plds + j);
  } else {
    // ---- weight transpose via LDS: dst[col][row] = src[row][col] (bf16) ----
    const int t = blk - 3072;           // 0..79
    const int proj = t >> 4, tile = t & 15;
    const int tr = (tile >> 2) * 64, tc = (tile & 3) * 64;
    const float* src = proj == 0 ? qw : proj == 1 ? kw : proj == 2 ? vw
                        : proj == 3 ? gw : ow;
    u16* dst = proj < 4 ? (Wt + proj * 65536) : OWt;
    const float scale = proj == 0 ? 0.17677669529663687f : 1.f;
    {
      const int rl = tid >> 2, cg = (tid & 3) * 16;
      const float* sp = src + (size_t)(tr + rl) * 256 + tc + cg;
      float4 a0 = *(const float4*)(sp);
      float4 a1 = *(const float4*)(sp + 4);
      float4 a2 = *(const float4*)(sp + 8);
      float4 a3 = *(const float4*)(sp + 12);
      float xs[16] = {a0.x, a0.y, a0.z, a0.w, a1.x, a1.y, a1.z, a1.w,
                      a2.x, a2.y, a2.z, a2.w, a3.x, a3.y, a3.z, a3.w};
#pragma unroll
      for (int j = 0; j < 16; j++)
        tlds[(cg + j) * 66 + rl] = f2b(xs[j] * scale);  // transposed store
    }
    __syncthreads();
    {
      const int cl = tid >> 2, ag = (tid & 3) * 16;
      union { uint4 q[2]; u16 u[16]; } uu;
#pragma unroll
      for (int j = 0; j < 16; j++) uu.u[j] = tlds[cl * 66 + ag + j];
      u16* dp = dst + (size_t)(tc + cl) * 256 + tr + ag;
      *(uint4*)(dp) = uu.q[0];
      *(uint4*)(dp + 8) = uu.q[1];
    }
  }
}

// ------ K4/K6: bf16 MFMA GEMM, A[M][256] @ Bt[N][256]^T, 128x128 tile,
//        global_load_lds(16B) staging into unpadded [128][32], BK=32 ------
template <bool OUT_BF16>
__global__ __launch_bounds__(256) void k_gemm(
    const u16* __restrict__ A, const u16* __restrict__ Bt,
    void* __restrict__ out, const float* __restrict__ obias, const int N) {
  __shared__ u16 As[128 * 32];
  __shared__ u16 Bs[128 * 32];
  const int tid = threadIdx.x, wid = tid >> 6, lane = tid & 63;
  const int quad = lane >> 4, l16 = lane & 15;
  const int wm = (wid >> 1) * 64, wn = (wid & 1) * 64;
  const int bm = blockIdx.x, bn = blockIdx.y;
  const int r0 = wid * 16 + (lane >> 2);
  const int kc = (lane & 3) * 8;
  const u16* gA0 = A + (size_t)(bm * 128 + r0) * 256 + kc;
  const u16* gA1 = A + (size_t)(bm * 128 + 64 + r0) * 256 + kc;
  const u16* gB0 = Bt + (size_t)(bn * 128 + r0) * 256 + kc;
  const u16* gB1 = Bt + (size_t)(bn * 128 + 64 + r0) * 256 + kc;
  u16* lA0 = As + wid * 512;
  u16* lA1 = As + 2048 + wid * 512;
  u16* lB0 = Bs + wid * 512;
  u16* lB1 = Bs + 2048 + wid * 512;
  f32x4 acc[4][4];
#pragma unroll
  for (int i = 0; i < 4; i++)
#pragma unroll
    for (int j = 0; j < 4; j++) acc[i][j] = f32x4{0.f, 0.f, 0.f, 0.f};
  for (int k0 = 0; k0 < 256; k0 += 32) {
    __syncthreads();
    load_lds16(gA0 + k0, lA0);
    load_lds16(gA1 + k0, lA1);
    load_lds16(gB0 + k0, lB0);
    load_lds16(gB1 + k0, lB1);
    __syncthreads();
    short8 af[4], bf[4];
#pragma unroll
    for (int i = 0; i < 4; i++)
      af[i] = *(const short8*)(As + (wm + i * 16 + l16) * 32 + quad * 8);
#pragma unroll
    for (int j = 0; j < 4; j++)
      bf[j] = *(const short8*)(Bs + (wn + j * 16 + l16) * 32 + quad * 8);
#pragma unroll
    for (int i = 0; i < 4; i++)
#pragma unroll
      for (int j = 0; j < 4; j++)
        acc[i][j] = __builtin_amdgcn_mfma_f32_16x16x32_bf16(af[i], bf[j], acc[i][j], 0, 0, 0);
  }
#pragma unroll
  for (int i = 0; i < 4; i++)
#pragma unroll
    for (int j = 0; j < 4; j++)
#pragma unroll
      for (int r = 0; r < 4; r++) {
        const int gm = bm * 128 + wm + i * 16 + quad * 4 + r;
        const int gn = bn * 128 + wn + j * 16 + l16;
        const float v = acc[i][j][r];
        if (OUT_BF16) ((u16*)out)[(size_t)gm * N + gn] = f2b(v);
        else ((float*)out)[(size_t)gm * N + gn] = v + obias[gn];
      }
}

// ---- K5: attention, block = (b, h, q-half): 512 thr = 8 waves x 16 q.
//      K in LDS (union-reused as P after softmax barrier); V^T permuted;
//      no max-subtraction (logits bounded; masked terms underflow to 0) ----
__global__ __launch_bounds__(512, 4) void k_attn(
    const u16* __restrict__ Y, const float* __restrict__ biasB,
    const float* __restrict__ mask, const float* __restrict__ gb,
    u16* __restrict__ Z) {
  __shared__ u16 KsPs[9216];   // Ks [256][32] (8192 u16), later per-wave Ps (8x1152)
  __shared__ u16 Vt[32 * 264]; // [c][slot], stride 264 = 8*33 (2-way-only aliasing)
  const int b = blockIdx.x, h = blockIdx.y, qh = blockIdx.z;
  const int tid = threadIdx.x, w = tid >> 6, lane = tid & 63;
  const int quad = lane >> 4, l16 = lane & 15;
  const int q0 = qh * 128 + w * 16;
  const u16* Yb = Y + (size_t)b * 256 * 1024;
  // ---- stage K [k][32c of head h] via async 16B loads (2 per wave) ----
  {
    const int kr = w * 32 + (lane >> 2), kc = (lane & 3) * 8;
    load_lds16(Yb + (size_t)kr * 1024 + 256 + h * 32 + kc, KsPs + (w * 32) * 32);
    load_lds16(Yb + (size_t)(kr + 16) * 1024 + 256 + h * 32 + kc, KsPs + (w * 32 + 16) * 32);
  }
  // ---- stage V^T permuted: thread t -> slot t&255, c-chunk (t>>8)*16 ----
  {
    const int slot = tid & 255, c0 = (tid >> 8) * 16;
    const int kv = ((slot >> 6) << 6) + ((slot & 3) << 4) + ((slot >> 2) & 15);
    const u16* src = Yb + (size_t)kv * 1024 + 512 + h * 32 + c0;
    union { uint4 q[2]; u16 u[16]; } uu;
    uu.q[0] = *(const uint4*)(src);
    uu.q[1] = *(const uint4*)(src + 8);
#pragma unroll
    for (int j = 0; j < 16; j++) Vt[(c0 + j) * 264 + slot] = uu.u[j];
  }
  // ---- Q frag + mask (global, before barrier) ----
  const short8 aq = *(const short8*)(Yb + (size_t)(q0 + l16) * 1024 + h * 32 + quad * 8);
  float maskv[16];
#pragma unroll
  for (int ni = 0; ni < 16; ni++)
    maskv[ni] = 1e9f * (mask[b * 256 + ni * 16 + l16] - 1.f);
  __syncthreads();  // K + V staging complete
  // ---- S = Q K^T : 16 MFMAs per wave ----
  f32x4 S[16];
#pragma unroll
  for (int ni = 0; ni < 16; ni++) S[ni] = f32x4{0.f, 0.f, 0.f, 0.f};
#pragma unroll
  for (int ni = 0; ni < 16; ni++) {
    const short8 bk = *(const short8*)(KsPs + (ni * 16 + l16) * 32 + quad * 8);
    S[ni] = __builtin_amdgcn_mfma_f32_16x16x32_bf16(aq, bk, S[ni], 0, 0, 0);
  }
  // ---- + permuted pair bias + mask; softmax over k WITHOUT max-sub ----
  float li[4];
#pragma unroll
  for (int r = 0; r < 4; r++) {
    const int qg = q0 + quad * 4 + r;
    const float* bb = biasB + (h << 16) + (qg << 8) + l16 * 4;
    const float4 b0 = *(const float4*)(bb);
    const float4 b1 = *(const float4*)(bb + 64);
    const float4 b2 = *(const float4*)(bb + 128);
    const float4 b3 = *(const float4*)(bb + 192);
    const float bv[16] = {b0.x, b0.y, b0.z, b0.w, b1.x, b1.y, b1.z, b1.w,
                          b2.x, b2.y, b2.z, b2.w, b3.x, b3.y, b3.z, b3.w};
    float l = 0.f;
#pragma unroll
    for (int ni = 0; ni < 16; ni++) {
      const float p = __expf(S[ni][r] + bv[ni] + maskv[ni]);
      S[ni][r] = p;
      l += p;
    }
#pragma unroll
    for (int d = 1; d < 16; d <<= 1) l += __shfl_xor(l, d);
    li[r] = __builtin_amdgcn_rcpf(l);
  }
  __syncthreads();  // all K-reads done; Ks region becomes per-wave Ps
  // ---- P @ V in 4 k-quarters through per-wave LDS (wave-in-order DS) ----
  f32x4 O[2];
  O[0] = f32x4{0.f, 0.f, 0.f, 0.f};
  O[1] = f32x4{0.f, 0.f, 0.f, 0.f};
  u16* Pw = KsPs + w * 1152;  // [16 q][72]
#pragma unroll
  for (int Q = 0; Q < 4; Q++) {
#pragma unroll
    for (int r = 0; r < 4; r++) {
      uint2 wv;  // slots l16*4..+3 of row quad*4+r
      wv.x = pkb(S[Q * 4 + 0][r], S[Q * 4 + 1][r]);
      wv.y = pkb(S[Q * 4 + 2][r], S[Q * 4 + 3][r]);
      *(uint2*)(Pw + (quad * 4 + r) * 72 + l16 * 4) = wv;
    }
#pragma unroll
    for (int ks = 0; ks < 2; ks++) {
      const short8 ap = *(const short8*)(Pw + l16 * 72 + ks * 32 + quad * 8);
#pragma unroll
      for (int nj = 0; nj < 2; nj++) {
        const short8 bv = *(const short8*)(Vt + (nj * 16 + l16) * 264 + Q * 64 + ks * 32 + quad * 8);
        O[nj] = __builtin_amdgcn_mfma_f32_16x16x32_bf16(ap, bv, O[nj], 0, 0, 0);
      }
    }
  }
  // ---- epilogue: 1/l, gate sigmoid, stage in Pw, coalesced 16B stores ----
  const float* gbh = gb + h * 32;
#pragma unroll
  for (int nj = 0; nj < 2; nj++)
#pragma unroll
    for (int r = 0; r < 4; r++) {
      const int qg = q0 + quad * 4 + r;
      const int c = nj * 16 + l16;
      const float wa = O[nj][r] * li[r];
      const float gv = b2f(Yb[(size_t)qg * 1024 + 768 + h * 32 + c]) + gbh[c];
      const float gate = __builtin_amdgcn_rcpf(1.f + __expf(-gv));
      Pw[(quad * 4 + r) * 40 + c] = f2b(wa * gate);
    }
  {
    const int qr = lane >> 2, cc = (lane & 3) * 8;
    const uint4 zv = *(const uint4*)(Pw + qr * 40 + cc);
    *(uint4*)(Z + ((size_t)(b * 256 + q0 + qr)) * 256 + h * 32 + cc) = zv;
  }
}

extern "C" void kernel_launch(void* const* d_in, const int* in_sizes, int n_in,
                              void* d_out, int out_size, void* d_ws, size_t ws_size,
                              hipStream_t stream) {
  const float* msa  = (const float*)d_in[0];
  const float* mask = (const float*)d_in[1];
  const float* pair = (const float*)d_in[2];
  const float* qns  = (const float*)d_in[3];
  const float* qnb  = (const float*)d_in[4];
  const float* pns  = (const float*)d_in[5];
  const float* pnb  = (const float*)d_in[6];
  const float* f2w  = (const float*)d_in[7];
  const float* qw   = (const float*)d_in[8];
  const float* kw   = (const float*)d_in[9];
  const float* vw   = (const float*)d_in[10];
  const float* gw   = (const float*)d_in[11];
  const float* gbp  = (const float*)d_in[12];
  const float* ow   = (const float*)d_in[13];
  const float* ob   = (const float*)d_in[14];
  float* out = (float*)d_out;
  char* ws = (char*)d_ws;
  u16*   xb    = (u16*)(ws);                  // 16777216 B
  u16*   Wt    = (u16*)(ws + 16777216);       //   524288 B
  u16*   OWt   = (u16*)(ws + 17301504);       //   131072 B
  float* biasB = (float*)(ws + 17432576);     //  2097152 B
  u16*   Y     = (u16*)(ws + 19529728);       // 67108864 B
  u16*   Z     = (u16*)(ws + 86638592);       // 16777216 B

  k_prep<<<3152, 256, 0, stream>>>(msa, qns, qnb, pair, pns, pnb, f2w,
                                   qw, kw, vw, gw, ow, xb, biasB, Wt, OWt);
  k_gemm<true><<<dim3(256, 8), 256, 0, stream>>>(xb, Wt, (void*)Y, nullptr, 1024);
  k_attn<<<dim3(128, 8, 2), 512, 0, stream>>>(Y, biasB, mask, gbp, Z);
  k_gemm<false><<<dim3(256, 2), 256, 0, stream>>>(Z, OWt, (void*)out, ob, 256);
}